// Round 13
// baseline (240.926 us; speedup 1.0000x reference)
//
#include <hip/hip_runtime.h>
#include <math.h>

typedef __attribute__((ext_vector_type(4)))  float f32x4;
typedef __attribute__((ext_vector_type(16))) float f32x16;
typedef __attribute__((ext_vector_type(8)))  short bf16x8;

#define NB   64
#define CD   128
#define TD   2048
#define QBLK 128             // per block (4 waves x 32 rows)
#define KVB  32
#define NKV  (TD / KVB)      // 64
#define NQT  (TD / QBLK)     // 16

#define TILE_B   8192        // K tile: [cblk 0..15][s 0..31] 16B ; V tile: [sblk 0..3][c 0..127] 16B
#define VBASE    ((size_t)NB * NKV * TILE_B)   // 33,554,432 (total ws = 64 MB)

__device__ __forceinline__ short f2bf(float f) {
    union { float f; unsigned u; } x; x.f = f;
    unsigned r = x.u + 0x7FFFu + ((x.u >> 16) & 1u);   // RNE
    return (short)(r >> 16);
}

// ---------------------------------------------------------------------------
// Prepass: K -> plane-major transposed tiles [cblk][s][8c], V -> plane-major
// natural tiles [sblk][c][8s]. Fragment loads then hit per-lane 16B chunks.
// (Unchanged from R7.)
// ---------------------------------------------------------------------------
__global__ __launch_bounds__(256)
void prepass(const float* __restrict__ qkv, char* __restrict__ ws)
{
    int blk  = blockIdx.x;            // 64 b * 64 (kind,sb)
    int b    = blk >> 6;
    int rem  = blk & 63;
    int kind = rem >> 5;              // 0=K, 1=V
    int sb   = rem & 31;              // 64-row source slab -> 2 tiles
    int s0   = sb * 64;
    int tid  = threadIdx.x;
    const float* src = qkv + ((size_t)b * 3 + 1 + kind) * CD * TD;

    if (kind == 0) {
        // K transpose: stage [s'][c] in LDS, emit plane-major tiles
        __shared__ short Tl[64][CD + 8];
        int su = (tid & 15) * 4;
        int cb = 4 * (tid >> 4);
        #pragma unroll
        for (int it = 0; it < 2; ++it) {
            int c0 = cb + 64 * it;
            f32x4 r0 = *(const f32x4*)&src[(size_t)(c0 + 0) * TD + s0 + su];
            f32x4 r1 = *(const f32x4*)&src[(size_t)(c0 + 1) * TD + s0 + su];
            f32x4 r2 = *(const f32x4*)&src[(size_t)(c0 + 2) * TD + s0 + su];
            f32x4 r3 = *(const f32x4*)&src[(size_t)(c0 + 3) * TD + s0 + su];
            #pragma unroll
            for (int s = 0; s < 4; ++s) {
                short4 w;
                w.x = f2bf(r0[s]); w.y = f2bf(r1[s]);
                w.z = f2bf(r2[s]); w.w = f2bf(r3[s]);
                *(short4*)&Tl[su + s][c0] = w;
            }
        }
        __syncthreads();
        char* kt0 = ws + ((size_t)b * NKV + 2 * sb) * TILE_B;
        #pragma unroll
        for (int it = 0; it < 4; ++it) {
            int row = (tid >> 4) + 16 * it;     // 0..63 source s
            int p   = tid & 15;                 // cblk
            *(f32x4*)(kt0 + (row >> 5) * TILE_B + p * 512 + (row & 31) * 16)
                = *(const f32x4*)&Tl[row][p * 8];
        }
    } else {
        // V: tile[sblk][c][8 s-values], contiguous 16B stores per (c, chunk)
        char* vt0 = ws + VBASE + ((size_t)b * NKV + 2 * sb) * TILE_B;
        int c  = tid >> 1;
        int hh = tid & 1;
        #pragma unroll
        for (int i = 0; i < 4; ++i) {
            int q = 4 * hh + i;                 // 8B-pair chunk 0..7 over 64 s
            f32x4 a0 = *(const f32x4*)&src[(size_t)c * TD + s0 + q * 8];
            f32x4 a1 = *(const f32x4*)&src[(size_t)c * TD + s0 + q * 8 + 4];
            bf16x8 w;
            w[0] = f2bf(a0[0]); w[1] = f2bf(a0[1]); w[2] = f2bf(a0[2]); w[3] = f2bf(a0[3]);
            w[4] = f2bf(a1[0]); w[5] = f2bf(a1[1]); w[6] = f2bf(a1[2]); w[7] = f2bf(a1[3]);
            *(bf16x8*)(vt0 + (q >> 2) * TILE_B + (q & 3) * 2048 + c * 16) = w;
        }
    }
}

// ---------------------------------------------------------------------------
// Attention: NO LDS, NO barriers, register diet for 3 waves/SIMD.
// Per iter: load K frags (QK waits) -> QK -> issue V frags -> softmax ->
// exchange -> PV (waits V). kf dead before vf live: peak regs <= ~165.
// ---------------------------------------------------------------------------
__global__ __launch_bounds__(256, 3)
void attn_fwd(const float* __restrict__ qkv, const char* __restrict__ ws,
              float* __restrict__ out)
{
    // XCD-bijective decode (grid 1024, 256t blocks: proven L2 locality)
    int i    = blockIdx.x;            // 1024 workgroups
    int xcd  = i & 7;
    int slot = i >> 3;                // 0..127
    int b    = xcd * 8 + (slot >> 4);
    int tt   = slot & 15;
    int t0   = tt * QBLK;

    int tid  = threadIdx.x;
    int wid  = tid >> 6;              // wave 0..3: rows [t0+32*wid, +32)
    int lane = tid & 63;
    int h    = lane >> 5;             // k-half
    int tcol = lane & 31;

    const char*  ktb = ws + (size_t)b * NKV * TILE_B;
    const char*  vtb = ws + VBASE + (size_t)b * NKV * TILE_B;
    const float* qb  = qkv + (size_t)b * 3 * CD * TD;

    int kbase = h * 512  + tcol * 16; // K frag: + kt*1024 (+ sb*TILE_B)
    int vbase = h * 2048 + tcol * 16; // V frag: + (f>>2)*4096 + (f&3)*512

    // ---- Q fragments fp32->bf16, scale*log2e folded. B[n=t][k=c] ----
    const float SCALE2 = 0.12751743f;   // log2(e)/sqrt(128)
    int tq = t0 + 32 * wid + tcol;
    bf16x8 qf[8];
    #pragma unroll
    for (int kt = 0; kt < 8; ++kt)
        #pragma unroll
        for (int j = 0; j < 8; ++j)
            qf[kt][j] = f2bf(qb[(size_t)(16 * kt + 8 * h + j) * TD + tq] * SCALE2);

    f32x16 o[4];
    #pragma unroll
    for (int mt = 0; mt < 4; ++mt) o[mt] = (f32x16)(0.0f);
    float m = -1e30f, lsum = 0.0f;    // per-lane (column tq) state

    #pragma unroll 1
    for (int sb = 0; sb < NKV; ++sb) {
        // ---- load K(sb) fragments; QK consumes them (compiler waitcnt) ----
        const char* kg = ktb + (size_t)sb * TILE_B;
        bf16x8 kf[8];
        #pragma unroll
        for (int kt = 0; kt < 8; ++kt)
            kf[kt] = *(const bf16x8*)(kg + kbase + kt * 1024);

        // ---- QK^T swapped: D[m=s][n=t] = sum_c K[s][c] Q[c][t] ----
        f32x16 acc = (f32x16)(0.0f);
        __builtin_amdgcn_s_setprio(1);
        #pragma unroll
        for (int kt = 0; kt < 8; ++kt)
            acc = __builtin_amdgcn_mfma_f32_32x32x16_bf16(kf[kt], qf[kt], acc, 0, 0, 0);
        __builtin_amdgcn_s_setprio(0);

        // ---- kf now dead: issue V(sb) loads (latency hides under softmax) ----
        const char* vg = vtb + (size_t)sb * TILE_B;
        bf16x8 vf[8];
        #pragma unroll
        for (int f = 0; f < 8; ++f)
            vf[f] = *(const bf16x8*)(vg + vbase + (f >> 2) * 4096 + (f & 3) * 512);

        // ---- softmax (exp2 domain), per-lane scalar state ----
        float px0 = fmaxf(fmaxf(acc[0], acc[4]),  fmaxf(acc[8],  acc[12]));
        float px1 = fmaxf(fmaxf(acc[1], acc[5]),  fmaxf(acc[9],  acc[13]));
        float px2 = fmaxf(fmaxf(acc[2], acc[6]),  fmaxf(acc[10], acc[14]));
        float px3 = fmaxf(fmaxf(acc[3], acc[7]),  fmaxf(acc[11], acc[15]));
        float pm = fmaxf(fmaxf(px0, px1), fmaxf(px2, px3));

        // defer-max: partial check equivalent to full under __all (lane^32 pair)
        if (!__all(pm <= m + 8.0f)) {
            float rm = fmaxf(pm, __shfl_xor(pm, 32, 64));
            rm = fmaxf(m, rm);
            float cr = exp2f(m - rm);
            m = rm;
            lsum *= cr;
            #pragma unroll
            for (int mt = 0; mt < 4; ++mt)
                #pragma unroll
                for (int r = 0; r < 16; ++r)
                    o[mt][r] *= cr;
        }
        float s0a = 0.f, s1a = 0.f, s2a = 0.f, s3a = 0.f;
        #pragma unroll
        for (int r = 0; r < 16; r += 4) {
            acc[r + 0] = exp2f(acc[r + 0] - m);
            acc[r + 1] = exp2f(acc[r + 1] - m);
            acc[r + 2] = exp2f(acc[r + 2] - m);
            acc[r + 3] = exp2f(acc[r + 3] - m);
            s0a += acc[r + 0];
            s1a += acc[r + 1];
            s2a += acc[r + 2];
            s3a += acc[r + 3];
        }
        lsum += (s0a + s1a) + (s2a + s3a);

        // ---- P^T -> PV B-frags in-register: cvt_pk + lane^32 exchange ----
        unsigned pfr[2][4];
        #pragma unroll
        for (int e = 0; e < 2; ++e) {
            unsigned k0_, k1_, k2_, k3_;
            asm("v_cvt_pk_bf16_f32 %0, %1, %2" : "=v"(k0_) : "v"(acc[8*e+0]), "v"(acc[8*e+1]));
            asm("v_cvt_pk_bf16_f32 %0, %1, %2" : "=v"(k1_) : "v"(acc[8*e+2]), "v"(acc[8*e+3]));
            asm("v_cvt_pk_bf16_f32 %0, %1, %2" : "=v"(k2_) : "v"(acc[8*e+4]), "v"(acc[8*e+5]));
            asm("v_cvt_pk_bf16_f32 %0, %1, %2" : "=v"(k3_) : "v"(acc[8*e+6]), "v"(acc[8*e+7]));
            unsigned sA = h ? k0_ : k2_;
            unsigned sB = h ? k1_ : k3_;
            unsigned r0 = (unsigned)__shfl_xor((int)sA, 32, 64);
            unsigned r1 = (unsigned)__shfl_xor((int)sB, 32, 64);
            pfr[e][0] = h ? r0 : k0_;
            pfr[e][1] = h ? r1 : k1_;
            pfr[e][2] = h ? k2_ : r0;
            pfr[e][3] = h ? k3_ : r1;
        }

        // ---- PV swapped: D[m=c][n=t] = sum_s V[c][s] P^T[s][t] ----
        __builtin_amdgcn_s_setprio(1);
        #pragma unroll
        for (int kt2 = 0; kt2 < 2; ++kt2) {
            union { unsigned u[4]; bf16x8 v; } pw;
            pw.u[0] = pfr[kt2][0]; pw.u[1] = pfr[kt2][1];
            pw.u[2] = pfr[kt2][2]; pw.u[3] = pfr[kt2][3];
            #pragma unroll
            for (int mt = 0; mt < 4; ++mt)
                o[mt] = __builtin_amdgcn_mfma_f32_32x32x16_bf16(vf[kt2 * 4 + mt], pw.v, o[mt], 0, 0, 0);
        }
        __builtin_amdgcn_s_setprio(0);
    }

    // ---- epilogue: finish denominator across lane^32 pair, store out[c][t] ----
    lsum += __shfl_xor(lsum, 32, 64);
    float inv = 1.0f / lsum;
    float* ob = out + (size_t)b * CD * TD;
    #pragma unroll
    for (int mt = 0; mt < 4; ++mt)
        #pragma unroll
        for (int r = 0; r < 16; ++r) {
            int c = 32 * mt + (r & 3) + 8 * (r >> 2) + 4 * h;
            ob[(size_t)c * TD + tq] = o[mt][r] * inv;
        }
}

extern "C" void kernel_launch(void* const* d_in, const int* in_sizes, int n_in,
                              void* d_out, int out_size, void* d_ws, size_t ws_size,
                              hipStream_t stream)
{
    const float* qkv = (const float*)d_in[0];
    float* out = (float*)d_out;
    char* ws = (char*)d_ws;
    prepass<<<dim3(NB * 64), 256, 0, stream>>>(qkv, ws);                   // 4096 wgs
    attn_fwd<<<dim3(NB * NQT), 256, 0, stream>>>(qkv, ws, out);            // 1024 wgs
}

// Round 14
// 202.863 us; speedup vs baseline: 1.1876x; 1.1876x over previous
//
#include <hip/hip_runtime.h>
#include <math.h>

typedef __attribute__((ext_vector_type(4)))  float f32x4;
typedef __attribute__((ext_vector_type(16))) float f32x16;
typedef __attribute__((ext_vector_type(8)))  short bf16x8;

#define NB   64
#define CD   128
#define TD   2048
#define QBLK 128             // per block (4 waves x 32 rows)
#define KVB  32
#define NKV  (TD / KVB)      // 64
#define NQT  (TD / QBLK)     // 16

#define TILE_B   8192        // K tile: [cblk 0..15][s 0..31] 16B ; V tile: [sblk 0..3][c 0..127] 16B
#define VBASE    ((size_t)NB * NKV * TILE_B)   // 33,554,432 (total ws = 64 MB)

__device__ __forceinline__ short f2bf(float f) {
    union { float f; unsigned u; } x; x.f = f;
    unsigned r = x.u + 0x7FFFu + ((x.u >> 16) & 1u);   // RNE
    return (short)(r >> 16);
}

__device__ __forceinline__ float ex2(float x) {      // raw v_exp_f32 (1 instr)
    return __builtin_amdgcn_exp2f(x);
}
__device__ __forceinline__ float mx3(float a, float b, float c) {
    return fmaxf(fmaxf(a, b), c);                    // fuses to v_max3_f32
}

__device__ __forceinline__ void gl_lds16(const void* g, void* l) {
    __builtin_amdgcn_global_load_lds(
        (__attribute__((address_space(1))) void*)g,
        (__attribute__((address_space(3))) void*)l, 16, 0, 0);
}

// ---------------------------------------------------------------------------
// Prepass: K -> plane-major transposed tiles [cblk][s][8c], V -> plane-major
// natural tiles [sblk][c][8s]. MFMA b128 reads then need no XOR swizzle.
// ---------------------------------------------------------------------------
__global__ __launch_bounds__(256)
void prepass(const float* __restrict__ qkv, char* __restrict__ ws)
{
    int blk  = blockIdx.x;            // 64 b * 64 (kind,sb)
    int b    = blk >> 6;
    int rem  = blk & 63;
    int kind = rem >> 5;              // 0=K, 1=V
    int sb   = rem & 31;              // 64-row source slab -> 2 tiles
    int s0   = sb * 64;
    int tid  = threadIdx.x;
    const float* src = qkv + ((size_t)b * 3 + 1 + kind) * CD * TD;

    if (kind == 0) {
        // K transpose: stage [s'][c] in LDS, emit plane-major tiles
        __shared__ short Tl[64][CD + 8];
        int su = (tid & 15) * 4;
        int cb = 4 * (tid >> 4);
        #pragma unroll
        for (int it = 0; it < 2; ++it) {
            int c0 = cb + 64 * it;
            f32x4 r0 = *(const f32x4*)&src[(size_t)(c0 + 0) * TD + s0 + su];
            f32x4 r1 = *(const f32x4*)&src[(size_t)(c0 + 1) * TD + s0 + su];
            f32x4 r2 = *(const f32x4*)&src[(size_t)(c0 + 2) * TD + s0 + su];
            f32x4 r3 = *(const f32x4*)&src[(size_t)(c0 + 3) * TD + s0 + su];
            #pragma unroll
            for (int s = 0; s < 4; ++s) {
                short4 w;
                w.x = f2bf(r0[s]); w.y = f2bf(r1[s]);
                w.z = f2bf(r2[s]); w.w = f2bf(r3[s]);
                *(short4*)&Tl[su + s][c0] = w;
            }
        }
        __syncthreads();
        char* kt0 = ws + ((size_t)b * NKV + 2 * sb) * TILE_B;
        #pragma unroll
        for (int it = 0; it < 4; ++it) {
            int row = (tid >> 4) + 16 * it;     // 0..63 source s
            int p   = tid & 15;                 // cblk
            *(f32x4*)(kt0 + (row >> 5) * TILE_B + p * 512 + (row & 31) * 16)
                = *(const f32x4*)&Tl[row][p * 8];
        }
    } else {
        // V: tile[sblk][c][8 s-values], contiguous 16B stores per (c, chunk)
        char* vt0 = ws + VBASE + ((size_t)b * NKV + 2 * sb) * TILE_B;
        int c  = tid >> 1;
        int hh = tid & 1;
        #pragma unroll
        for (int i = 0; i < 4; ++i) {
            int q = 4 * hh + i;                 // 8B-pair chunk 0..7 over 64 s
            f32x4 a0 = *(const f32x4*)&src[(size_t)c * TD + s0 + q * 8];
            f32x4 a1 = *(const f32x4*)&src[(size_t)c * TD + s0 + q * 8 + 4];
            bf16x8 w;
            w[0] = f2bf(a0[0]); w[1] = f2bf(a0[1]); w[2] = f2bf(a0[2]); w[3] = f2bf(a0[3]);
            w[4] = f2bf(a1[0]); w[5] = f2bf(a1[1]); w[6] = f2bf(a1[2]); w[7] = f2bf(a1[3]);
            *(bf16x8*)(vt0 + (q >> 2) * TILE_B + (q & 3) * 2048 + c * 16) = w;
        }
    }
}

// ---------------------------------------------------------------------------
// Attention: R7 structure (4 blocks/CU, KVB=32 double-buffer, 1 barrier/iter,
// plane-major conflict-free reads) + VALU diet (raw v_exp_f32, v_max3 trees).
// ---------------------------------------------------------------------------
__global__ __launch_bounds__(256, 4)
void attn_fwd(const float* __restrict__ qkv, const char* __restrict__ ws,
              float* __restrict__ out)
{
    // XCD-bijective decode (256t blocks: i&7 mapping is HW-verified here)
    int i    = blockIdx.x;            // 1024 workgroups
    int xcd  = i & 7;
    int slot = i >> 3;                // 0..127
    int b    = xcd * 8 + (slot >> 4);
    int tt   = slot & 15;
    int t0   = tt * QBLK;

    int tid  = threadIdx.x;
    int wid  = tid >> 6;              // wave 0..3: rows [t0+32*wid, +32)
    int lane = tid & 63;
    int h    = lane >> 5;             // k-half
    int tcol = lane & 31;

    const char*  ktb = ws + (size_t)b * NKV * TILE_B;
    const char*  vtb = ws + VBASE + (size_t)b * NKV * TILE_B;
    const float* qb  = qkv + (size_t)b * 3 * CD * TD;

    __shared__ short Klds[2][KVB * CD];  // 2 x 8KB plane-major
    __shared__ short Vlds[2][CD * KVB];  // 2 x 8KB plane-major
    char* k0 = (char*)&Klds[0][0];
    char* k1 = (char*)&Klds[1][0];
    char* v0 = (char*)&Vlds[0][0];
    char* v1 = (char*)&Vlds[1][0];

    int wb = wid * 1024;              // per-wave 64 lanes x 16B
    int lo = lane * 16;
    int kbase = h * 512  + tcol * 16; // K read: + kt*1024
    int vbase = h * 2048 + tcol * 16; // V read: + kt2*4096 + mt*512

    // ---- Q fragments fp32->bf16, scale*log2e folded. B[n=t][k=c] ----
    const float SCALE2 = 0.12751743f;   // log2(e)/sqrt(128)
    int tq = t0 + 32 * wid + tcol;
    bf16x8 qf[8];
    #pragma unroll
    for (int kt = 0; kt < 8; ++kt)
        #pragma unroll
        for (int j = 0; j < 8; ++j)
            qf[kt][j] = f2bf(qb[(size_t)(16 * kt + 8 * h + j) * TD + tq] * SCALE2);
    __builtin_amdgcn_sched_barrier(0);

    // ---- prologue: stage tile 0 into buffer 0 (K then V) ----
    #pragma unroll
    for (int it = 0; it < 2; ++it)
        gl_lds16(ktb + it * 4096 + wb + lo, k0 + it * 4096 + wb);
    #pragma unroll
    for (int it = 0; it < 2; ++it)
        gl_lds16(vtb + it * 4096 + wb + lo, v0 + it * 4096 + wb);

    f32x16 o[4];
    #pragma unroll
    for (int mt = 0; mt < 4; ++mt) o[mt] = (f32x16)(0.0f);
    float m = -1e30f, lsum = 0.0f;    // per-lane (column tq) state

    auto ITER = [&](int sb, char* kc, char* vc, char* kn, char* vn)
        __attribute__((always_inline))
    {
        int nxt = (sb + 1 < NKV) ? (sb + 1) : sb;   // clamped: uniform pipeline

        // ---- tile sb resident; all waves done reading the other buffer ----
        asm volatile("s_waitcnt vmcnt(0)" ::: "memory");
        __builtin_amdgcn_sched_barrier(0);
        __builtin_amdgcn_s_barrier();
        __builtin_amdgcn_sched_barrier(0);

        // ---- prefetch tile sb+1 into the other buffer ----
        {
            const char* kg = ktb + (size_t)nxt * TILE_B;
            const char* vg = vtb + (size_t)nxt * TILE_B;
            #pragma unroll
            for (int it = 0; it < 2; ++it)
                gl_lds16(kg + it * 4096 + wb + lo, kn + it * 4096 + wb);
            #pragma unroll
            for (int it = 0; it < 2; ++it)
                gl_lds16(vg + it * 4096 + wb + lo, vn + it * 4096 + wb);
        }

        // ---- QK^T swapped: D[m=s][n=t] = sum_c K[s][c] Q[c][t] ----
        f32x16 acc = (f32x16)(0.0f);
        __builtin_amdgcn_s_setprio(1);
        #pragma unroll
        for (int kt = 0; kt < 8; ++kt) {
            bf16x8 kf = *(const bf16x8*)(kc + kbase + kt * 1024);
            acc = __builtin_amdgcn_mfma_f32_32x32x16_bf16(kf, qf[kt], acc, 0, 0, 0);
        }
        __builtin_amdgcn_s_setprio(0);

        // ---- softmax (exp2 domain), VALU-diet: max3 tree + raw v_exp ----
        float t1 = mx3(acc[0],  acc[1],  acc[2]);
        float t2 = mx3(acc[3],  acc[4],  acc[5]);
        float t3 = mx3(acc[6],  acc[7],  acc[8]);
        float t4 = mx3(acc[9],  acc[10], acc[11]);
        float t5 = mx3(acc[12], acc[13], acc[14]);
        float pm = mx3(mx3(t1, t2, t3), mx3(t4, t5, acc[15]), m - 1e30f);
        pm = fmaxf(pm, mx3(t4, t5, acc[15]));   // (redundant-safe; folded below)
        pm = mx3(mx3(t1, t2, t3), mx3(t4, t5, acc[15]), -1e30f);

        // defer-max: partial check equivalent to full under __all (lane^32 pair)
        if (!__all(pm <= m + 8.0f)) {
            float rm = fmaxf(pm, __shfl_xor(pm, 32, 64));
            rm = fmaxf(m, rm);
            float cr = ex2(m - rm);
            m = rm;
            lsum *= cr;
            #pragma unroll
            for (int mt = 0; mt < 4; ++mt)
                #pragma unroll
                for (int r = 0; r < 16; ++r)
                    o[mt][r] *= cr;
        }
        float s0a = 0.f, s1a = 0.f, s2a = 0.f, s3a = 0.f;
        #pragma unroll
        for (int r = 0; r < 16; r += 4) {
            acc[r + 0] = ex2(acc[r + 0] - m);
            acc[r + 1] = ex2(acc[r + 1] - m);
            acc[r + 2] = ex2(acc[r + 2] - m);
            acc[r + 3] = ex2(acc[r + 3] - m);
            s0a += acc[r + 0];
            s1a += acc[r + 1];
            s2a += acc[r + 2];
            s3a += acc[r + 3];
        }
        lsum += (s0a + s1a) + (s2a + s3a);

        // ---- P^T -> PV B-frags in-register: cvt_pk + lane^32 exchange ----
        unsigned pb[2][4];
        #pragma unroll
        for (int e = 0; e < 2; ++e) {
            unsigned k0_, k1_, k2_, k3_;
            asm("v_cvt_pk_bf16_f32 %0, %1, %2" : "=v"(k0_) : "v"(acc[8*e+0]), "v"(acc[8*e+1]));
            asm("v_cvt_pk_bf16_f32 %0, %1, %2" : "=v"(k1_) : "v"(acc[8*e+2]), "v"(acc[8*e+3]));
            asm("v_cvt_pk_bf16_f32 %0, %1, %2" : "=v"(k2_) : "v"(acc[8*e+4]), "v"(acc[8*e+5]));
            asm("v_cvt_pk_bf16_f32 %0, %1, %2" : "=v"(k3_) : "v"(acc[8*e+6]), "v"(acc[8*e+7]));
            unsigned sA = h ? k0_ : k2_;
            unsigned sB = h ? k1_ : k3_;
            unsigned r0 = (unsigned)__shfl_xor((int)sA, 32, 64);
            unsigned r1 = (unsigned)__shfl_xor((int)sB, 32, 64);
            pb[e][0] = h ? r0 : k0_;
            pb[e][1] = h ? r1 : k1_;
            pb[e][2] = h ? k2_ : r0;
            pb[e][3] = h ? k3_ : r1;
        }

        // ---- PV swapped: D[m=c][n=t] = sum_s V[c][s] P^T[s][t] ----
        __builtin_amdgcn_s_setprio(1);
        #pragma unroll
        for (int kt2 = 0; kt2 < 2; ++kt2) {
            union { unsigned u[4]; bf16x8 v; } pw;
            pw.u[0] = pb[kt2][0]; pw.u[1] = pb[kt2][1];
            pw.u[2] = pb[kt2][2]; pw.u[3] = pb[kt2][3];
            #pragma unroll
            for (int mt = 0; mt < 4; ++mt) {
                bf16x8 vf = *(const bf16x8*)(vc + vbase + kt2 * 4096 + mt * 512);
                o[mt] = __builtin_amdgcn_mfma_f32_32x32x16_bf16(vf, pw.v, o[mt], 0, 0, 0);
            }
        }
        __builtin_amdgcn_s_setprio(0);
    };

    #pragma unroll 1
    for (int s2 = 0; s2 < NKV; s2 += 2) {
        ITER(s2,     k0, v0, k1, v1);
        ITER(s2 + 1, k1, v1, k0, v0);
    }

    // drain redundant tail prefetch before exit
    asm volatile("s_waitcnt vmcnt(0)" ::: "memory");
    __builtin_amdgcn_sched_barrier(0);

    // ---- epilogue: finish denominator across lane^32 pair, store out[c][t] ----
    lsum += __shfl_xor(lsum, 32, 64);
    float inv = 1.0f / lsum;
    float* ob = out + (size_t)b * CD * TD;
    #pragma unroll
    for (int mt = 0; mt < 4; ++mt)
        #pragma unroll
        for (int r = 0; r < 16; ++r) {
            int c = 32 * mt + (r & 3) + 8 * (r >> 2) + 4 * h;
            ob[(size_t)c * TD + tq] = o[mt][r] * inv;
        }
}

extern "C" void kernel_launch(void* const* d_in, const int* in_sizes, int n_in,
                              void* d_out, int out_size, void* d_ws, size_t ws_size,
                              hipStream_t stream)
{
    const float* qkv = (const float*)d_in[0];
    float* out = (float*)d_out;
    char* ws = (char*)d_ws;
    prepass<<<dim3(NB * 64), 256, 0, stream>>>(qkv, ws);                   // 4096 wgs
    attn_fwd<<<dim3(NB * NQT), 256, 0, stream>>>(qkv, ws, out);            // 1024 wgs
}

// Round 15
// 195.472 us; speedup vs baseline: 1.2325x; 1.0378x over previous
//
#include <hip/hip_runtime.h>
#include <math.h>

typedef __attribute__((ext_vector_type(4)))  float f32x4;
typedef __attribute__((ext_vector_type(16))) float f32x16;
typedef __attribute__((ext_vector_type(8)))  short bf16x8;

#define NB   64
#define CD   128
#define TD   2048
#define QBLK 256             // per block (4 waves x 64 rows, dual 32-col tiles)
#define KVB  32
#define NKV  (TD / KVB)      // 64
#define NQT  (TD / QBLK)     // 8

#define TILE_B   8192        // K tile: [cblk 0..15][s 0..31] 16B ; V tile: [sblk 0..3][c 0..127] 16B
#define VBASE    ((size_t)NB * NKV * TILE_B)   // 33,554,432 (total ws = 64 MB)

__device__ __forceinline__ short f2bf(float f) {
    union { float f; unsigned u; } x; x.f = f;
    unsigned r = x.u + 0x7FFFu + ((x.u >> 16) & 1u);   // RNE
    return (short)(r >> 16);
}

__device__ __forceinline__ float ex2(float x) {      // raw v_exp_f32 (1 instr)
    return __builtin_amdgcn_exp2f(x);
}
__device__ __forceinline__ float mx3(float a, float b, float c) {
    return fmaxf(fmaxf(a, b), c);                    // fuses to v_max3_f32
}

__device__ __forceinline__ void gl_lds16(const void* g, void* l) {
    __builtin_amdgcn_global_load_lds(
        (__attribute__((address_space(1))) void*)g,
        (__attribute__((address_space(3))) void*)l, 16, 0, 0);
}

// ---------------------------------------------------------------------------
// Prepass: K -> plane-major transposed tiles [cblk][s][8c], V -> plane-major
// natural tiles [sblk][c][8s]. MFMA b128 reads then need no XOR swizzle.
// ---------------------------------------------------------------------------
__global__ __launch_bounds__(256)
void prepass(const float* __restrict__ qkv, char* __restrict__ ws)
{
    int blk  = blockIdx.x;            // 64 b * 64 (kind,sb)
    int b    = blk >> 6;
    int rem  = blk & 63;
    int kind = rem >> 5;              // 0=K, 1=V
    int sb   = rem & 31;              // 64-row source slab -> 2 tiles
    int s0   = sb * 64;
    int tid  = threadIdx.x;
    const float* src = qkv + ((size_t)b * 3 + 1 + kind) * CD * TD;

    if (kind == 0) {
        // K transpose: stage [s'][c] in LDS, emit plane-major tiles
        __shared__ short Tl[64][CD + 8];
        int su = (tid & 15) * 4;
        int cb = 4 * (tid >> 4);
        #pragma unroll
        for (int it = 0; it < 2; ++it) {
            int c0 = cb + 64 * it;
            f32x4 r0 = *(const f32x4*)&src[(size_t)(c0 + 0) * TD + s0 + su];
            f32x4 r1 = *(const f32x4*)&src[(size_t)(c0 + 1) * TD + s0 + su];
            f32x4 r2 = *(const f32x4*)&src[(size_t)(c0 + 2) * TD + s0 + su];
            f32x4 r3 = *(const f32x4*)&src[(size_t)(c0 + 3) * TD + s0 + su];
            #pragma unroll
            for (int s = 0; s < 4; ++s) {
                short4 w;
                w.x = f2bf(r0[s]); w.y = f2bf(r1[s]);
                w.z = f2bf(r2[s]); w.w = f2bf(r3[s]);
                *(short4*)&Tl[su + s][c0] = w;
            }
        }
        __syncthreads();
        char* kt0 = ws + ((size_t)b * NKV + 2 * sb) * TILE_B;
        #pragma unroll
        for (int it = 0; it < 4; ++it) {
            int row = (tid >> 4) + 16 * it;     // 0..63 source s
            int p   = tid & 15;                 // cblk
            *(f32x4*)(kt0 + (row >> 5) * TILE_B + p * 512 + (row & 31) * 16)
                = *(const f32x4*)&Tl[row][p * 8];
        }
    } else {
        // V: tile[sblk][c][8 s-values], contiguous 16B stores per (c, chunk)
        char* vt0 = ws + VBASE + ((size_t)b * NKV + 2 * sb) * TILE_B;
        int c  = tid >> 1;
        int hh = tid & 1;
        #pragma unroll
        for (int i = 0; i < 4; ++i) {
            int q = 4 * hh + i;                 // 8B-pair chunk 0..7 over 64 s
            f32x4 a0 = *(const f32x4*)&src[(size_t)c * TD + s0 + q * 8];
            f32x4 a1 = *(const f32x4*)&src[(size_t)c * TD + s0 + q * 8 + 4];
            bf16x8 w;
            w[0] = f2bf(a0[0]); w[1] = f2bf(a0[1]); w[2] = f2bf(a0[2]); w[3] = f2bf(a0[3]);
            w[4] = f2bf(a1[0]); w[5] = f2bf(a1[1]); w[6] = f2bf(a1[2]); w[7] = f2bf(a1[3]);
            *(bf16x8*)(vt0 + (q >> 2) * TILE_B + (q & 3) * 2048 + c * 16) = w;
        }
    }
}

// ---------------------------------------------------------------------------
// Attention: dual 32-col tiles per wave (shared K/V ds_reads halve LDS-pipe
// pressure), grid 512 = balanced 2 blocks/CU, VALU diet (v_exp_f32, v_max3).
// ---------------------------------------------------------------------------
__global__ __launch_bounds__(256, 2)
void attn_fwd(const float* __restrict__ qkv, const char* __restrict__ ws,
              float* __restrict__ out)
{
    // XCD-bijective decode (256t blocks: i&7 round-robin is HW-verified)
    int i    = blockIdx.x;            // 512 workgroups
    int xcd  = i & 7;
    int slot = i >> 3;                // 0..63
    int b    = xcd * 8 + (slot >> 3);
    int tt   = slot & 7;
    int t0   = tt * QBLK;

    int tid  = threadIdx.x;
    int wid  = tid >> 6;              // wave 0..3: rows [t0+64*wid, +64)
    int lane = tid & 63;
    int h    = lane >> 5;             // k-half
    int tcol = lane & 31;

    const char*  ktb = ws + (size_t)b * NKV * TILE_B;
    const char*  vtb = ws + VBASE + (size_t)b * NKV * TILE_B;
    const float* qb  = qkv + (size_t)b * 3 * CD * TD;

    __shared__ short Klds[2][KVB * CD];  // 2 x 8KB plane-major
    __shared__ short Vlds[2][CD * KVB];  // 2 x 8KB plane-major
    char* k0 = (char*)&Klds[0][0];
    char* k1 = (char*)&Klds[1][0];
    char* v0 = (char*)&Vlds[0][0];
    char* v1 = (char*)&Vlds[1][0];

    int wb = wid * 1024;              // per-wave 64 lanes x 16B
    int lo = lane * 16;
    int kbase = h * 512  + tcol * 16; // K read: + kt*1024
    int vbase = h * 2048 + tcol * 16; // V read: + kt2*4096 + mt*512

    // ---- Q fragments fp32->bf16, scale*log2e folded. Two column tiles. ----
    const float SCALE2 = 0.12751743f;   // log2(e)/sqrt(128)
    int tq = t0 + 64 * wid + tcol;      // ntile0 col; ntile1 col = tq+32
    bf16x8 qf0[8], qf1[8];
    #pragma unroll
    for (int kt = 0; kt < 8; ++kt)
        #pragma unroll
        for (int j = 0; j < 8; ++j) {
            size_t row = (size_t)(16 * kt + 8 * h + j) * TD;
            qf0[kt][j] = f2bf(qb[row + tq] * SCALE2);
            qf1[kt][j] = f2bf(qb[row + tq + 32] * SCALE2);
        }
    __builtin_amdgcn_sched_barrier(0);

    // ---- prologue: stage tile 0 into buffer 0 (K then V) ----
    #pragma unroll
    for (int it = 0; it < 2; ++it)
        gl_lds16(ktb + it * 4096 + wb + lo, k0 + it * 4096 + wb);
    #pragma unroll
    for (int it = 0; it < 2; ++it)
        gl_lds16(vtb + it * 4096 + wb + lo, v0 + it * 4096 + wb);

    f32x16 o0[4], o1[4];
    #pragma unroll
    for (int mt = 0; mt < 4; ++mt) { o0[mt] = (f32x16)(0.0f); o1[mt] = (f32x16)(0.0f); }
    float m0 = -1e30f, lsum0 = 0.0f;
    float m1 = -1e30f, lsum1 = 0.0f;

    auto ITER = [&](int sb, char* kc, char* vc, char* kn, char* vn)
        __attribute__((always_inline))
    {
        int nxt = (sb + 1 < NKV) ? (sb + 1) : sb;   // clamped: uniform pipeline

        // ---- tile sb resident; all waves done reading the other buffer ----
        asm volatile("s_waitcnt vmcnt(0)" ::: "memory");
        __builtin_amdgcn_sched_barrier(0);
        __builtin_amdgcn_s_barrier();
        __builtin_amdgcn_sched_barrier(0);

        // ---- prefetch tile sb+1 into the other buffer ----
        {
            const char* kg = ktb + (size_t)nxt * TILE_B;
            const char* vg = vtb + (size_t)nxt * TILE_B;
            #pragma unroll
            for (int it = 0; it < 2; ++it)
                gl_lds16(kg + it * 4096 + wb + lo, kn + it * 4096 + wb);
            #pragma unroll
            for (int it = 0; it < 2; ++it)
                gl_lds16(vg + it * 4096 + wb + lo, vn + it * 4096 + wb);
        }

        // ---- QK^T swapped, dual n-tile: each kf feeds two MFMAs ----
        f32x16 acc0 = (f32x16)(0.0f), acc1 = (f32x16)(0.0f);
        __builtin_amdgcn_s_setprio(1);
        #pragma unroll
        for (int kt = 0; kt < 8; ++kt) {
            bf16x8 kf = *(const bf16x8*)(kc + kbase + kt * 1024);
            acc0 = __builtin_amdgcn_mfma_f32_32x32x16_bf16(kf, qf0[kt], acc0, 0, 0, 0);
            acc1 = __builtin_amdgcn_mfma_f32_32x32x16_bf16(kf, qf1[kt], acc1, 0, 0, 0);
        }
        __builtin_amdgcn_s_setprio(0);

        // ---- softmax (exp2 domain), VALU diet: max3 trees + raw v_exp ----
        float pm0, pm1;
        {
            float t1 = mx3(acc0[0],  acc0[1],  acc0[2]);
            float t2 = mx3(acc0[3],  acc0[4],  acc0[5]);
            float t3 = mx3(acc0[6],  acc0[7],  acc0[8]);
            float t4 = mx3(acc0[9],  acc0[10], acc0[11]);
            float t5 = mx3(acc0[12], acc0[13], acc0[14]);
            pm0 = fmaxf(mx3(t1, t2, t3), mx3(t4, t5, acc0[15]));
        }
        {
            float t1 = mx3(acc1[0],  acc1[1],  acc1[2]);
            float t2 = mx3(acc1[3],  acc1[4],  acc1[5]);
            float t3 = mx3(acc1[6],  acc1[7],  acc1[8]);
            float t4 = mx3(acc1[9],  acc1[10], acc1[11]);
            float t5 = mx3(acc1[12], acc1[13], acc1[14]);
            pm1 = fmaxf(mx3(t1, t2, t3), mx3(t4, t5, acc1[15]));
        }

        int okk = (pm0 <= m0 + 8.0f) && (pm1 <= m1 + 8.0f);
        if (!__all(okk)) {
            float rm0 = fmaxf(m0, fmaxf(pm0, __shfl_xor(pm0, 32, 64)));
            float rm1 = fmaxf(m1, fmaxf(pm1, __shfl_xor(pm1, 32, 64)));
            float cr0 = ex2(m0 - rm0);
            float cr1 = ex2(m1 - rm1);
            m0 = rm0; m1 = rm1;
            lsum0 *= cr0; lsum1 *= cr1;
            #pragma unroll
            for (int mt = 0; mt < 4; ++mt)
                #pragma unroll
                for (int r = 0; r < 16; ++r) {
                    o0[mt][r] *= cr0;
                    o1[mt][r] *= cr1;
                }
        }
        {
            float s0a = 0.f, s1a = 0.f, s2a = 0.f, s3a = 0.f;
            #pragma unroll
            for (int r = 0; r < 16; r += 4) {
                acc0[r + 0] = ex2(acc0[r + 0] - m0);
                acc0[r + 1] = ex2(acc0[r + 1] - m0);
                acc0[r + 2] = ex2(acc0[r + 2] - m0);
                acc0[r + 3] = ex2(acc0[r + 3] - m0);
                s0a += acc0[r + 0]; s1a += acc0[r + 1];
                s2a += acc0[r + 2]; s3a += acc0[r + 3];
            }
            lsum0 += (s0a + s1a) + (s2a + s3a);
        }
        {
            float s0a = 0.f, s1a = 0.f, s2a = 0.f, s3a = 0.f;
            #pragma unroll
            for (int r = 0; r < 16; r += 4) {
                acc1[r + 0] = ex2(acc1[r + 0] - m1);
                acc1[r + 1] = ex2(acc1[r + 1] - m1);
                acc1[r + 2] = ex2(acc1[r + 2] - m1);
                acc1[r + 3] = ex2(acc1[r + 3] - m1);
                s0a += acc1[r + 0]; s1a += acc1[r + 1];
                s2a += acc1[r + 2]; s3a += acc1[r + 3];
            }
            lsum1 += (s0a + s1a) + (s2a + s3a);
        }

        // ---- P^T -> PV B-frags in-register: cvt_pk + lane^32 exchange ----
        unsigned p0[2][4], p1[2][4];
        #pragma unroll
        for (int e = 0; e < 2; ++e) {
            unsigned k0_, k1_, k2_, k3_;
            asm("v_cvt_pk_bf16_f32 %0, %1, %2" : "=v"(k0_) : "v"(acc0[8*e+0]), "v"(acc0[8*e+1]));
            asm("v_cvt_pk_bf16_f32 %0, %1, %2" : "=v"(k1_) : "v"(acc0[8*e+2]), "v"(acc0[8*e+3]));
            asm("v_cvt_pk_bf16_f32 %0, %1, %2" : "=v"(k2_) : "v"(acc0[8*e+4]), "v"(acc0[8*e+5]));
            asm("v_cvt_pk_bf16_f32 %0, %1, %2" : "=v"(k3_) : "v"(acc0[8*e+6]), "v"(acc0[8*e+7]));
            unsigned sA = h ? k0_ : k2_;
            unsigned sB = h ? k1_ : k3_;
            unsigned r0 = (unsigned)__shfl_xor((int)sA, 32, 64);
            unsigned r1 = (unsigned)__shfl_xor((int)sB, 32, 64);
            p0[e][0] = h ? r0 : k0_;
            p0[e][1] = h ? r1 : k1_;
            p0[e][2] = h ? k2_ : r0;
            p0[e][3] = h ? k3_ : r1;
        }
        #pragma unroll
        for (int e = 0; e < 2; ++e) {
            unsigned k0_, k1_, k2_, k3_;
            asm("v_cvt_pk_bf16_f32 %0, %1, %2" : "=v"(k0_) : "v"(acc1[8*e+0]), "v"(acc1[8*e+1]));
            asm("v_cvt_pk_bf16_f32 %0, %1, %2" : "=v"(k1_) : "v"(acc1[8*e+2]), "v"(acc1[8*e+3]));
            asm("v_cvt_pk_bf16_f32 %0, %1, %2" : "=v"(k2_) : "v"(acc1[8*e+4]), "v"(acc1[8*e+5]));
            asm("v_cvt_pk_bf16_f32 %0, %1, %2" : "=v"(k3_) : "v"(acc1[8*e+6]), "v"(acc1[8*e+7]));
            unsigned sA = h ? k0_ : k2_;
            unsigned sB = h ? k1_ : k3_;
            unsigned r0 = (unsigned)__shfl_xor((int)sA, 32, 64);
            unsigned r1 = (unsigned)__shfl_xor((int)sB, 32, 64);
            p1[e][0] = h ? r0 : k0_;
            p1[e][1] = h ? r1 : k1_;
            p1[e][2] = h ? k2_ : r0;
            p1[e][3] = h ? k3_ : r1;
        }

        // ---- PV swapped, dual n-tile: each vf feeds two MFMAs ----
        __builtin_amdgcn_s_setprio(1);
        #pragma unroll
        for (int kt2 = 0; kt2 < 2; ++kt2) {
            union { unsigned u[4]; bf16x8 v; } w0, w1;
            w0.u[0] = p0[kt2][0]; w0.u[1] = p0[kt2][1];
            w0.u[2] = p0[kt2][2]; w0.u[3] = p0[kt2][3];
            w1.u[0] = p1[kt2][0]; w1.u[1] = p1[kt2][1];
            w1.u[2] = p1[kt2][2]; w1.u[3] = p1[kt2][3];
            #pragma unroll
            for (int mt = 0; mt < 4; ++mt) {
                bf16x8 vf = *(const bf16x8*)(vc + vbase + kt2 * 4096 + mt * 512);
                o0[mt] = __builtin_amdgcn_mfma_f32_32x32x16_bf16(vf, w0.v, o0[mt], 0, 0, 0);
                o1[mt] = __builtin_amdgcn_mfma_f32_32x32x16_bf16(vf, w1.v, o1[mt], 0, 0, 0);
            }
        }
        __builtin_amdgcn_s_setprio(0);
    };

    #pragma unroll 1
    for (int s2 = 0; s2 < NKV; s2 += 2) {
        ITER(s2,     k0, v0, k1, v1);
        ITER(s2 + 1, k1, v1, k0, v0);
    }

    // drain redundant tail prefetch before exit
    asm volatile("s_waitcnt vmcnt(0)" ::: "memory");
    __builtin_amdgcn_sched_barrier(0);

    // ---- epilogue: finish denominators across lane^32 pair, store ----
    lsum0 += __shfl_xor(lsum0, 32, 64);
    lsum1 += __shfl_xor(lsum1, 32, 64);
    float inv0 = 1.0f / lsum0;
    float inv1 = 1.0f / lsum1;
    float* ob = out + (size_t)b * CD * TD;
    #pragma unroll
    for (int mt = 0; mt < 4; ++mt)
        #pragma unroll
        for (int r = 0; r < 16; ++r) {
            int c = 32 * mt + (r & 3) + 8 * (r >> 2) + 4 * h;
            ob[(size_t)c * TD + tq]      = o0[mt][r] * inv0;
            ob[(size_t)c * TD + tq + 32] = o1[mt][r] * inv1;
        }
}

extern "C" void kernel_launch(void* const* d_in, const int* in_sizes, int n_in,
                              void* d_out, int out_size, void* d_ws, size_t ws_size,
                              hipStream_t stream)
{
    const float* qkv = (const float*)d_in[0];
    float* out = (float*)d_out;
    char* ws = (char*)d_ws;
    prepass<<<dim3(NB * 64), 256, 0, stream>>>(qkv, ws);                   // 4096 wgs
    attn_fwd<<<dim3(NB * NQT), 256, 0, stream>>>(qkv, ws, out);            // 512 wgs
}